// Round 1
// baseline (617.903 us; speedup 1.0000x reference)
//
#include <hip/hip_runtime.h>
#include <hip/hip_bf16.h>

// Problem constants (from reference):
// N=50000, C_IN=256, D=25000, K=16, C_OUT=256
// y[d,k,:] = (x[n]*symm_norm[n]) @ (w[:256]+w[256:]) + b, n = domains[d,k]
// => z[n,:] = xs[n,:] @ weff + b  (GEMM, [50000,256]x[256,256])
//    y[r,:] = z[domains[r],:]     (gather, 400000 rows)

#define GM 50000
#define GK 256
#define GN 256
#define BM 64
#define BN 64
#define BK 16

// Tiled fp32 GEMM: z[m,n] = sum_k x[m,k]*sn[m]*(w[k,n]+w[k+256,n]) + b[n]
// 256 threads/block, each computes a 4x4 micro-tile of a 64x64 block tile.
__global__ __launch_bounds__(256)
void gemm_z_kernel(const float* __restrict__ x,
                   const float* __restrict__ sn,
                   const float* __restrict__ w,
                   const float* __restrict__ b,
                   float* __restrict__ z) {
    __shared__ float As[BM][BK + 1];   // +1 pad breaks pow2 strides
    __shared__ float Bs[BK][BN];

    const int t  = threadIdx.x;
    const int tx = t & 15;             // 16 cols of threads
    const int ty = t >> 4;             // 16 rows of threads
    const int rowBase = blockIdx.x * BM;
    const int colBase = blockIdx.y * BN;

    float acc[4][4] = {};

    // A-tile load mapping: 4 elems/thread, coalesced 16-wide rows
    const int la_col = t & 15;         // k within tile
    const int la_row = t >> 4;         // 0..15, +i*16
    // B-tile load mapping: 64-wide coalesced rows
    const int lb_col = t & 63;
    const int lb_row = t >> 6;         // 0..3, kk = lb_row + i*4

    for (int k0 = 0; k0 < GK; k0 += BK) {
        // stage A (scaled by symm_norm) and B (weff = w_top + w_bot)
        #pragma unroll
        for (int i = 0; i < 4; ++i) {
            int r = la_row + i * 16;
            int m = rowBase + r;
            float v = 0.0f;
            if (m < GM) v = x[(size_t)m * GK + k0 + la_col] * sn[m];
            As[r][la_col] = v;
        }
        #pragma unroll
        for (int i = 0; i < 4; ++i) {
            int kk = lb_row + i * 4;
            int gk = k0 + kk;
            int gn = colBase + lb_col;
            Bs[kk][lb_col] = w[(size_t)gk * GN + gn] +
                             w[(size_t)(gk + 256) * GN + gn];
        }
        __syncthreads();

        #pragma unroll
        for (int kk = 0; kk < BK; ++kk) {
            float a[4], bb[4];
            #pragma unroll
            for (int i = 0; i < 4; ++i) a[i]  = As[ty * 4 + i][kk];
            #pragma unroll
            for (int j = 0; j < 4; ++j) bb[j] = Bs[kk][tx * 4 + j];
            #pragma unroll
            for (int i = 0; i < 4; ++i)
                #pragma unroll
                for (int j = 0; j < 4; ++j)
                    acc[i][j] += a[i] * bb[j];
        }
        __syncthreads();
    }

    // epilogue: add bias, vectorized float4 store
    const int gn0 = colBase + tx * 4;
    const float4 bias = *reinterpret_cast<const float4*>(&b[gn0]);
    #pragma unroll
    for (int i = 0; i < 4; ++i) {
        int m = rowBase + ty * 4 + i;
        if (m < GM) {
            float4 v;
            v.x = acc[i][0] + bias.x;
            v.y = acc[i][1] + bias.y;
            v.z = acc[i][2] + bias.z;
            v.w = acc[i][3] + bias.w;
            *reinterpret_cast<float4*>(&z[(size_t)m * GN + gn0]) = v;
        }
    }
}

// Gather: out[r, :] = z[domains[r], :]. One wave per output row (1 KB),
// 4 rows per 256-thread block, float4 per lane -> fully coalesced 1 KB
// reads and writes.
__global__ __launch_bounds__(256)
void gather_kernel(const float* __restrict__ z,
                   const int* __restrict__ domains,
                   float* __restrict__ out,
                   int R) {
    const int r = blockIdx.x * 4 + (threadIdx.x >> 6);
    if (r >= R) return;
    const int c = (threadIdx.x & 63) * 4;
    const int n = domains[r];
    const float4 v = *reinterpret_cast<const float4*>(&z[(size_t)n * GN + c]);
    *reinterpret_cast<float4*>(&out[(size_t)r * GN + c]) = v;
}

extern "C" void kernel_launch(void* const* d_in, const int* in_sizes, int n_in,
                              void* d_out, int out_size, void* d_ws, size_t ws_size,
                              hipStream_t stream) {
    const float* x  = (const float*)d_in[0];   // [50000, 256]
    const float* sn = (const float*)d_in[1];   // [50000]
    const int*   dm = (const int*)d_in[2];     // [25000, 16] (int32 per harness)
    const float* w  = (const float*)d_in[3];   // [512, 256]
    const float* b  = (const float*)d_in[4];   // [256]
    float* out = (float*)d_out;                // [25000, 16, 256]
    float* z   = (float*)d_ws;                 // [50000, 256] scratch (51.2 MB)

    dim3 gemm_grid((GM + BM - 1) / BM, GN / BN);   // (782, 4)
    gemm_z_kernel<<<gemm_grid, 256, 0, stream>>>(x, sn, w, b, z);

    const int R = 25000 * 16;                      // 400000 output rows
    gather_kernel<<<(R + 3) / 4, 256, 0, stream>>>(z, dm, out, R);
}